// Round 7
// baseline (408.285 us; speedup 1.0000x reference)
//
#include <hip/hip_runtime.h>
#include <hip/hip_fp16.h>

static inline int idiv_up(long a, long b) { return (int)((a + b - 1) / b); }

#define RADIAL_G 8192

__device__ __forceinline__ unsigned pack_h2(float a, float b) {
    __half2 t = __floats2half2_rn(a, b);
    return *reinterpret_cast<unsigned*>(&t);
}
__device__ __forceinline__ unsigned short pack_h1(float a) {
    __half t = __float2half_rn(a);
    return *reinterpret_cast<unsigned short*>(&t);
}
__device__ __forceinline__ void unp_h2(unsigned u, float& lo, float& hi) {
    __half2 t = *reinterpret_cast<__half2*>(&u);
    lo = __half2float(__low2half(t));
    hi = __half2float(__high2half(t));
}
__device__ __forceinline__ float unp_h1(unsigned short u) {
    return __half2float(*reinterpret_cast<__half*>(&u));
}

// DPP cross-lane on the VALU pipe (no DS traffic).
template <int CTRL>
__device__ __forceinline__ float dppf(float x) {
    return __int_as_float(__builtin_amdgcn_update_dpp(
        0, __float_as_int(x), CTRL, 0xF, 0xF, true));
}
// all-lane sum within each 16-lane row
__device__ __forceinline__ float row_allsum(float p) {
    p += dppf<0xB1>(p);    // quad_perm xor1
    p += dppf<0x4E>(p);    // quad_perm xor2
    p += dppf<0x124>(p);   // row_ror:4
    p += dppf<0x128>(p);   // row_ror:8
    return p;
}

// ---------------------------------------------------------------------------
// Kernel 0: fold weights. Wcomb[f][j] = sum_c W_emb[f][c]*Wcat[c][j]
// j: [0,128)=Q (h=j>>5,k=j&31), [128,256)=K, [256,320)=V0
// ---------------------------------------------------------------------------
__global__ __launch_bounds__(256) void fold_weights(
    const float* __restrict__ W_emb, const float* __restrict__ b_emb,
    const float* __restrict__ Wq, const float* __restrict__ Wk,
    const float* __restrict__ Wv0,
    float* __restrict__ Wcomb, float* __restrict__ bcomb)
{
    int idx = blockIdx.x * 256 + threadIdx.x;
    if (idx >= 33 * 320) return;
    int row = idx / 320, j = idx - row * 320;
    float acc = 0.f;
    for (int c = 0; c < 64; ++c) {
        float w;
        if (j < 128)      { int h = j >> 5,         k = j & 31;         w = Wq [(h * 64 + c) * 32 + k]; }
        else if (j < 256) { int h = (j - 128) >> 5, k = (j - 128) & 31; w = Wk [(h * 64 + c) * 32 + k]; }
        else              { int h = (j - 256) >> 4, v = (j - 256) & 15; w = Wv0[(h * 64 + c) * 16 + v]; }
        float lhs = (row < 32) ? W_emb[row * 64 + c] : b_emb[c];
        acc += lhs * w;
    }
    if (row < 32) Wcomb[row * 320 + j] = acc;
    else          bcomb[j] = acc;
}

// ---------------------------------------------------------------------------
// Kernel 1: per-node tables; nf read ONCE per node, 10 column-chunks looped
// inside the block.
//   Qtab[n][128] f32
//   KVt[n]: 96 u32 slots (384B): [0..64) = half2(k_j,k_j+16) at lane h*16+j;
//   [64..96) = 64 u16 f16 V at lane h*16+j.
// ---------------------------------------------------------------------------
__global__ __launch_bounds__(256) void node_qkv(
    const float* __restrict__ nf, const float* __restrict__ Wcomb,
    const float* __restrict__ bcomb, float* __restrict__ Qtab,
    unsigned* __restrict__ KVt, int Nn)
{
    __shared__ float sW[32][32];
    __shared__ float sb[32];
    int n = blockIdx.x * 256 + threadIdx.x;
    bool valid = n < Nn;

    float nfv[32];
    if (valid) {
        const float4* nfp = (const float4*)(nf + (size_t)n * 32);
#pragma unroll
        for (int f4 = 0; f4 < 8; ++f4) {
            float4 v = nfp[f4];
            nfv[f4 * 4 + 0] = v.x; nfv[f4 * 4 + 1] = v.y;
            nfv[f4 * 4 + 2] = v.z; nfv[f4 * 4 + 3] = v.w;
        }
    }
    for (int c = 0; c < 10; ++c) {
        __syncthreads();
        for (int i = threadIdx.x; i < 1024; i += 256) {
            int f = i >> 5, jj = i & 31;
            sW[f][jj] = Wcomb[f * 320 + c * 32 + jj];
        }
        if (threadIdx.x < 32) sb[threadIdx.x] = bcomb[c * 32 + threadIdx.x];
        __syncthreads();
        if (!valid) continue;

        float acc[32];
#pragma unroll
        for (int jj = 0; jj < 32; ++jj) acc[jj] = sb[jj];
#pragma unroll
        for (int f = 0; f < 32; ++f) {
            float x = nfv[f];
#pragma unroll
            for (int j4 = 0; j4 < 8; ++j4) {
                float4 w = *(const float4*)&sW[f][j4 * 4];
                acc[j4 * 4 + 0] += x * w.x; acc[j4 * 4 + 1] += x * w.y;
                acc[j4 * 4 + 2] += x * w.z; acc[j4 * 4 + 3] += x * w.w;
            }
        }
        if (c < 4) {
            float4* outp = (float4*)(Qtab + (size_t)n * 128 + c * 32);
#pragma unroll
            for (int j4 = 0; j4 < 8; ++j4) {
                float4 v;
                v.x = acc[j4 * 4 + 0]; v.y = acc[j4 * 4 + 1];
                v.z = acc[j4 * 4 + 2]; v.w = acc[j4 * 4 + 3];
                outp[j4] = v;
            }
        } else if (c < 8) {
            unsigned* kp = KVt + (size_t)n * 96 + (c - 4) * 16;
#pragma unroll
            for (int jj = 0; jj < 16; ++jj)
                kp[jj] = pack_h2(acc[jj], acc[jj + 16]);
        } else {
            unsigned short* vp = (unsigned short*)(KVt + (size_t)n * 96 + 64) + (c - 8) * 32;
#pragma unroll
            for (int jj = 0; jj < 32; ++jj) vp[jj] = pack_h1(acc[jj]);
        }
    }
}

// ---------------------------------------------------------------------------
// Kernel 2: degree count
// ---------------------------------------------------------------------------
__global__ __launch_bounds__(256) void count_deg(
    const int* __restrict__ ei, int* __restrict__ deg, int Ee)
{
    int e = blockIdx.x * 256 + threadIdx.x;
    if (e >= Ee) return;
    atomicAdd(&deg[ei[Ee + e]], 1);
}

// ---------------------------------------------------------------------------
// Kernel 3: offsets via wave prefix-sum + one atomic per wave (order-free).
// ---------------------------------------------------------------------------
__global__ __launch_bounds__(256) void calc_offs(
    const int* __restrict__ deg, int* __restrict__ offs,
    int* __restrict__ cursor, int* __restrict__ gtot, int Nn)
{
    int n = blockIdx.x * 256 + threadIdx.x;
    int lane = threadIdx.x & 63;
    int d = (n < Nn) ? deg[n] : 0;
    int pre = d;
#pragma unroll
    for (int s = 1; s < 64; s <<= 1) {
        int t = __shfl_up(pre, s);
        if (lane >= s) pre += t;
    }
    int waveTot = __shfl(pre, 63);
    int base = 0;
    if (lane == 63) base = atomicAdd(gtot, waveTot);
    base = __shfl(base, 63);
    if (n < Nn) {
        int off = base + pre - d;
        offs[n] = off; cursor[n] = off;
    }
}

// ---------------------------------------------------------------------------
// Kernel 4: scatter edges into CSR-by-dst; pack (src, d) as int2.
// Also computes dmax (wave-reduced, 1 atomic/wave; positive-float == int order).
// ---------------------------------------------------------------------------
__global__ __launch_bounds__(256) void scatter_edges(
    const float* __restrict__ pos, const int* __restrict__ ei,
    int* __restrict__ cursor, int2* __restrict__ csr,
    int* __restrict__ dmax_enc, int Ee)
{
    int e = blockIdx.x * 256 + threadIdx.x;
    bool valid = e < Ee;
    float d = 0.f;
    int s = 0, dg = 0;
    if (valid) {
        s  = ei[e];
        dg = ei[Ee + e];
        float dx = pos[(size_t)dg * 3 + 0] - pos[(size_t)s * 3 + 0];
        float dy = pos[(size_t)dg * 3 + 1] - pos[(size_t)s * 3 + 1];
        float dz = pos[(size_t)dg * 3 + 2] - pos[(size_t)s * 3 + 2];
        d = sqrtf(dx * dx + dy * dy + dz * dz) + 1e-8f;
    }
    float wm = d;
#pragma unroll
    for (int i = 1; i < 64; i <<= 1) wm = fmaxf(wm, __shfl_xor(wm, i));
    if ((threadIdx.x & 63) == 0) atomicMax(dmax_enc, __float_as_int(wm));
    if (valid) {
        int p = atomicAdd(&cursor[dg], 1);
        int2 pk; pk.x = s; pk.y = __float_as_int(d);
        csr[p] = pk;
    }
}

// ---------------------------------------------------------------------------
// Kernel 5: radial lookup table over d in [0, dmax], G grid points.
//   TAB[g]: 96 u32 slots: [0..64) half2(rk0*rs, rk1*rs) at lane h*16+j,
//           [64..96) 64 u16 f16 rv.
// ---------------------------------------------------------------------------
__global__ __launch_bounds__(256) void build_tab(
    const float* __restrict__ R1, const float* __restrict__ b1,
    const float* __restrict__ R2, const float* __restrict__ b2,
    const int* __restrict__ dmax_enc, unsigned* __restrict__ TAB)
{
    int idx = blockIdx.x * 256 + threadIdx.x;
    if (idx >= RADIAL_G * 64) return;
    int g = idx >> 6, lane = idx & 63;
    int h = lane >> 4, j = lane & 15;
    float dmax = __int_as_float(*dmax_enc);
    float d = dmax * (float)g / (float)(RADIAL_G - 1);
    float rh[16];
#pragma unroll
    for (int r = 0; r < 16; ++r) {
        float x = fmaf(d, R1[h * 16 + r], b1[h * 16 + r]);
        rh[r] = x / (1.f + __expf(-x));
    }
    float rk0 = b2[h * 64 + j], rk1 = b2[h * 64 + j + 16], rv = b2[h * 64 + 32 + j];
#pragma unroll
    for (int r = 0; r < 16; ++r) {
        const float* row = R2 + (size_t)(h * 16 + r) * 64;
        rk0 = fmaf(rh[r], row[j], rk0);
        rk1 = fmaf(rh[r], row[j + 16], rk1);
        rv  = fmaf(rh[r], row[32 + j], rv);
    }
    const float rs = 0.17677669529663687f; // 1/sqrt(32) folded into rk
    TAB[(size_t)g * 96 + lane] = pack_h2(rk0 * rs, rk1 * rs);
    ((unsigned short*)(TAB + (size_t)g * 96 + 64))[lane] = pack_h1(rv);
}

// ---------------------------------------------------------------------------
// Kernel 6: fused per-node attention — table-driven radial, no online max.
// One wave per node. Lane: h=lane>>4, j=lane&15.
// Per edge: 1 wave-uniform csr load, 1 coalesced TAB row, 1 gathered KV row,
// score + DPP row-allsum + exp; loop-carried state = 2 independent FMAs.
// ---------------------------------------------------------------------------
__global__ __launch_bounds__(256) void node_attn(
    const float* __restrict__ Qtab, const unsigned* __restrict__ KVt,
    const unsigned* __restrict__ TAB, const int2* __restrict__ csr,
    const int* __restrict__ offs, const int* __restrict__ deg,
    const int* __restrict__ batch, const int* __restrict__ dmax_enc,
    float* __restrict__ pooled, int Nn)
{
    int lane = threadIdx.x & 63;
    int h = lane >> 4, j = lane & 15;
    int n = blockIdx.x * 4 + (threadIdx.x >> 6);
    if (n >= Nn) return;
    int start = offs[n], cnt = deg[n];
    if (cnt == 0) return;

    float dscale = (float)(RADIAL_G - 1) / __int_as_float(*dmax_enc);
    float q0 = Qtab[(size_t)n * 128 + h * 32 + j];
    float q1 = Qtab[(size_t)n * 128 + h * 32 + j + 16];
    float l = 0.f, acc = 0.f;

    auto LD = [&](int ei, unsigned& ku, unsigned short& vu,
                  unsigned& tk, unsigned short& tv) {
        int2 pk = csr[ei];
        int g = (int)fminf(fmaf(__int_as_float(pk.y), dscale, 0.5f),
                           (float)(RADIAL_G - 1));
        const unsigned* tb = TAB + (size_t)g * 96;
        tk = tb[lane];
        tv = ((const unsigned short*)(tb + 64))[lane];
        const unsigned* kb = KVt + (size_t)pk.x * 96;
        ku = kb[lane];
        vu = ((const unsigned short*)(kb + 64))[lane];
    };

    int e = start, end = start + cnt;
    unsigned ku0 = 0, ku1 = 0, tk0 = 0, tk1 = 0;
    unsigned short vu0 = 0, vu1 = 0, tv0 = 0, tv1 = 0;
    if (e + 1 < end) { LD(e, ku0, vu0, tk0, tv0); LD(e + 1, ku1, vu1, tk1, tv1); }
    for (; e + 1 < end; e += 2) {
        unsigned cku0 = ku0, ctk0 = tk0, cku1 = ku1, ctk1 = tk1;
        unsigned short cvu0 = vu0, ctv0 = tv0, cvu1 = vu1, ctv1 = tv1;
        if (e + 3 < end) { LD(e + 2, ku0, vu0, tk0, tv0); LD(e + 3, ku1, vu1, tk1, tv1); }
        float kx0, ky0, rx0, ry0, kx1, ky1, rx1, ry1;
        unp_h2(cku0, kx0, ky0); unp_h2(ctk0, rx0, ry0);
        unp_h2(cku1, kx1, ky1); unp_h2(ctk1, rx1, ry1);
        float p0 = q0 * kx0 * rx0 + q1 * ky0 * ry0;
        float p1 = q0 * kx1 * rx1 + q1 * ky1 * ry1;
        p0 = row_allsum(p0);
        p1 = row_allsum(p1);
        float ex0 = __expf(fminf(p0, 80.f));
        float ex1 = __expf(fminf(p1, 80.f));
        l += ex0 + ex1;
        acc = fmaf(ex0, unp_h1(cvu0) * unp_h1(ctv0),
              fmaf(ex1, unp_h1(cvu1) * unp_h1(ctv1), acc));
    }
    if (e < end) {
        unsigned ku, tk; unsigned short vu, tv;
        LD(e, ku, vu, tk, tv);
        float kx, ky, rx, ry;
        unp_h2(ku, kx, ky); unp_h2(tk, rx, ry);
        float p = q0 * kx * rx + q1 * ky * ry;
        p = row_allsum(p);
        float ex = __expf(fminf(p, 80.f));
        l += ex;
        acc = fmaf(ex, unp_h1(vu) * unp_h1(tv), acc);
    }
    float o = acc / (l + 1e-30f);
    atomicAdd(&pooled[(size_t)batch[n] * 64 + lane], o);
}

// ---------------------------------------------------------------------------
// Kernel 7: out[b][o] = sum_i pooled[b][i] * Wproj[i][o]
// ---------------------------------------------------------------------------
__global__ __launch_bounds__(256) void final_proj(
    const float* __restrict__ pooled, const float* __restrict__ Wproj,
    float* __restrict__ out, int total)
{
    int idx = blockIdx.x * 256 + threadIdx.x;
    if (idx >= total) return;
    int b = idx >> 6, o = idx & 63;
    float acc = 0.f;
#pragma unroll
    for (int i = 0; i < 64; ++i) acc += pooled[b * 64 + i] * Wproj[i * 64 + o];
    out[idx] = acc;
}

extern "C" void kernel_launch(void* const* d_in, const int* in_sizes, int n_in,
                              void* d_out, int out_size, void* d_ws, size_t ws_size,
                              hipStream_t stream)
{
    const float* pos   = (const float*)d_in[0];
    const float* nf    = (const float*)d_in[1];
    const int*   ei    = (const int*)d_in[2];
    const int*   batch = (const int*)d_in[3];
    const float* W_emb = (const float*)d_in[4];
    const float* b_emb = (const float*)d_in[5];
    const float* Wq    = (const float*)d_in[6];
    const float* Wk    = (const float*)d_in[7];
    const float* Wv0   = (const float*)d_in[8];
    const float* R1    = (const float*)d_in[10];
    const float* b1    = (const float*)d_in[11];
    const float* R2    = (const float*)d_in[12];
    const float* b2    = (const float*)d_in[13];
    const float* Wproj = (const float*)d_in[14];
    float* out = (float*)d_out;

    long Nn = in_sizes[0] / 3;
    long Ee = in_sizes[2] / 2;
    int  Bb = out_size / 64;

    float* ws = (float*)d_ws;
    size_t o = 0;
    size_t WCOMB = o; o += 32 * 320;
    size_t BCOMB = o; o += 320;
    size_t QTAB  = o; o += (size_t)Nn * 128;
    size_t KVT   = o; o += (size_t)Nn * 96;
    size_t DEG   = o; o += (size_t)Nn;
    size_t GTOT  = o; o += 2;                  // [0]=edge-total cursor, [1]=dmax
    size_t POOL  = o; o += (size_t)Bb * 64;
    size_t OFFS  = o; o += (size_t)Nn;
    size_t CURS  = o; o += (size_t)Nn;
    o = (o + 1) & ~(size_t)1;                  // 8B-align csr
    size_t CSR   = o; o += (size_t)Ee * 2;
    size_t TAB   = o; o += (size_t)RADIAL_G * 96;

    // zero deg + gtot + dmax + pooled (contiguous)
    hipMemsetAsync(ws + DEG, 0,
                   ((size_t)Nn + 2 + (size_t)Bb * 64) * sizeof(float), stream);

    fold_weights<<<idiv_up(33 * 320, 256), 256, 0, stream>>>(
        W_emb, b_emb, Wq, Wk, Wv0, ws + WCOMB, ws + BCOMB);

    node_qkv<<<idiv_up(Nn, 256), 256, 0, stream>>>(
        nf, ws + WCOMB, ws + BCOMB, ws + QTAB, (unsigned*)(ws + KVT), (int)Nn);

    count_deg<<<idiv_up(Ee, 256), 256, 0, stream>>>(
        ei, (int*)(ws + DEG), (int)Ee);

    calc_offs<<<idiv_up(Nn, 256), 256, 0, stream>>>(
        (const int*)(ws + DEG), (int*)(ws + OFFS), (int*)(ws + CURS),
        (int*)(ws + GTOT), (int)Nn);

    scatter_edges<<<idiv_up(Ee, 256), 256, 0, stream>>>(
        pos, ei, (int*)(ws + CURS), (int2*)(ws + CSR),
        (int*)(ws + GTOT) + 1, (int)Ee);

    build_tab<<<idiv_up(RADIAL_G * 64, 256), 256, 0, stream>>>(
        R1, b1, R2, b2, (const int*)(ws + GTOT) + 1, (unsigned*)(ws + TAB));

    node_attn<<<idiv_up(Nn, 4), 256, 0, stream>>>(
        ws + QTAB, (const unsigned*)(ws + KVT), (const unsigned*)(ws + TAB),
        (const int2*)(ws + CSR), (const int*)(ws + OFFS),
        (const int*)(ws + DEG), batch, (const int*)(ws + GTOT) + 1,
        ws + POOL, (int)Nn);

    final_proj<<<idiv_up(out_size, 256), 256, 0, stream>>>(
        ws + POOL, Wproj, out, out_size);
}

// Round 8
// 297.138 us; speedup vs baseline: 1.3741x; 1.3741x over previous
//
#include <hip/hip_runtime.h>
#include <hip/hip_fp16.h>

static inline int idiv_up(long a, long b) { return (int)((a + b - 1) / b); }

#define RADIAL_G 2048

__device__ __forceinline__ unsigned pack_h2(float a, float b) {
    __half2 t = __floats2half2_rn(a, b);
    return *reinterpret_cast<unsigned*>(&t);
}
__device__ __forceinline__ unsigned short pack_h1(float a) {
    __half t = __float2half_rn(a);
    return *reinterpret_cast<unsigned short*>(&t);
}
__device__ __forceinline__ void unp_h2(unsigned u, float& lo, float& hi) {
    __half2 t = *reinterpret_cast<__half2*>(&u);
    lo = __half2float(__low2half(t));
    hi = __half2float(__high2half(t));
}
__device__ __forceinline__ float unp_h1(unsigned short u) {
    return __half2float(*reinterpret_cast<__half*>(&u));
}

// DPP cross-lane on the VALU pipe (no DS traffic).
template <int CTRL>
__device__ __forceinline__ float dppf(float x) {
    return __int_as_float(__builtin_amdgcn_update_dpp(
        0, __float_as_int(x), CTRL, 0xF, 0xF, true));
}
// all-lane sum within each 16-lane row
__device__ __forceinline__ float row_allsum(float p) {
    p += dppf<0xB1>(p);    // quad_perm xor1
    p += dppf<0x4E>(p);    // quad_perm xor2
    p += dppf<0x124>(p);   // row_ror:4
    p += dppf<0x128>(p);   // row_ror:8
    return p;
}

// ---------------------------------------------------------------------------
// Kernel 0: fold weights. Wcomb[f][j] = sum_c W_emb[f][c]*Wcat[c][j]
// j: [0,128)=Q (h=j>>5,k=j&31), [128,256)=K, [256,320)=V0
// ---------------------------------------------------------------------------
__global__ __launch_bounds__(256) void fold_weights(
    const float* __restrict__ W_emb, const float* __restrict__ b_emb,
    const float* __restrict__ Wq, const float* __restrict__ Wk,
    const float* __restrict__ Wv0,
    float* __restrict__ Wcomb, float* __restrict__ bcomb)
{
    int idx = blockIdx.x * 256 + threadIdx.x;
    if (idx >= 33 * 320) return;
    int row = idx / 320, j = idx - row * 320;
    float acc = 0.f;
    for (int c = 0; c < 64; ++c) {
        float w;
        if (j < 128)      { int h = j >> 5,         k = j & 31;         w = Wq [(h * 64 + c) * 32 + k]; }
        else if (j < 256) { int h = (j - 128) >> 5, k = (j - 128) & 31; w = Wk [(h * 64 + c) * 32 + k]; }
        else              { int h = (j - 256) >> 4, v = (j - 256) & 15; w = Wv0[(h * 64 + c) * 16 + v]; }
        float lhs = (row < 32) ? W_emb[row * 64 + c] : b_emb[c];
        acc += lhs * w;
    }
    if (row < 32) Wcomb[row * 320 + j] = acc;
    else          bcomb[j] = acc;
}

// ---------------------------------------------------------------------------
// Kernel 1: per-node tables; nf read ONCE per node, 10 column-chunks looped
// inside the block.
//   Qtab[n][128] f32
//   KVt[n]: 96 u32 slots (384B): [0..64) = half2(k_j,k_j+16) at lane h*16+j;
//   [64..96) = 64 u16 f16 V at lane h*16+j.
// ---------------------------------------------------------------------------
__global__ __launch_bounds__(256) void node_qkv(
    const float* __restrict__ nf, const float* __restrict__ Wcomb,
    const float* __restrict__ bcomb, float* __restrict__ Qtab,
    unsigned* __restrict__ KVt, int Nn)
{
    __shared__ float sW[32][32];
    __shared__ float sb[32];
    int n = blockIdx.x * 256 + threadIdx.x;
    bool valid = n < Nn;

    float nfv[32];
    if (valid) {
        const float4* nfp = (const float4*)(nf + (size_t)n * 32);
#pragma unroll
        for (int f4 = 0; f4 < 8; ++f4) {
            float4 v = nfp[f4];
            nfv[f4 * 4 + 0] = v.x; nfv[f4 * 4 + 1] = v.y;
            nfv[f4 * 4 + 2] = v.z; nfv[f4 * 4 + 3] = v.w;
        }
    }
    for (int c = 0; c < 10; ++c) {
        __syncthreads();
        for (int i = threadIdx.x; i < 1024; i += 256) {
            int f = i >> 5, jj = i & 31;
            sW[f][jj] = Wcomb[f * 320 + c * 32 + jj];
        }
        if (threadIdx.x < 32) sb[threadIdx.x] = bcomb[c * 32 + threadIdx.x];
        __syncthreads();
        if (!valid) continue;

        float acc[32];
#pragma unroll
        for (int jj = 0; jj < 32; ++jj) acc[jj] = sb[jj];
#pragma unroll
        for (int f = 0; f < 32; ++f) {
            float x = nfv[f];
#pragma unroll
            for (int j4 = 0; j4 < 8; ++j4) {
                float4 w = *(const float4*)&sW[f][j4 * 4];
                acc[j4 * 4 + 0] += x * w.x; acc[j4 * 4 + 1] += x * w.y;
                acc[j4 * 4 + 2] += x * w.z; acc[j4 * 4 + 3] += x * w.w;
            }
        }
        if (c < 4) {
            float4* outp = (float4*)(Qtab + (size_t)n * 128 + c * 32);
#pragma unroll
            for (int j4 = 0; j4 < 8; ++j4) {
                float4 v;
                v.x = acc[j4 * 4 + 0]; v.y = acc[j4 * 4 + 1];
                v.z = acc[j4 * 4 + 2]; v.w = acc[j4 * 4 + 3];
                outp[j4] = v;
            }
        } else if (c < 8) {
            unsigned* kp = KVt + (size_t)n * 96 + (c - 4) * 16;
#pragma unroll
            for (int jj = 0; jj < 16; ++jj)
                kp[jj] = pack_h2(acc[jj], acc[jj + 16]);
        } else {
            unsigned short* vp = (unsigned short*)(KVt + (size_t)n * 96 + 64) + (c - 8) * 32;
#pragma unroll
            for (int jj = 0; jj < 32; ++jj) vp[jj] = pack_h1(acc[jj]);
        }
    }
}

// ---------------------------------------------------------------------------
// Kernel 2: degree count
// ---------------------------------------------------------------------------
__global__ __launch_bounds__(256) void count_deg(
    const int* __restrict__ ei, int* __restrict__ deg, int Ee)
{
    int e = blockIdx.x * 256 + threadIdx.x;
    if (e >= Ee) return;
    atomicAdd(&deg[ei[Ee + e]], 1);
}

// ---------------------------------------------------------------------------
// Kernel 3: offsets via wave prefix-sum + one atomic per wave (order-free).
// ---------------------------------------------------------------------------
__global__ __launch_bounds__(256) void calc_offs(
    const int* __restrict__ deg, int* __restrict__ offs,
    int* __restrict__ cursor, int* __restrict__ gtot, int Nn)
{
    int n = blockIdx.x * 256 + threadIdx.x;
    int lane = threadIdx.x & 63;
    int d = (n < Nn) ? deg[n] : 0;
    int pre = d;
#pragma unroll
    for (int s = 1; s < 64; s <<= 1) {
        int t = __shfl_up(pre, s);
        if (lane >= s) pre += t;
    }
    int waveTot = __shfl(pre, 63);
    int base = 0;
    if (lane == 63) base = atomicAdd(gtot, waveTot);
    base = __shfl(base, 63);
    if (n < Nn) {
        int off = base + pre - d;
        offs[n] = off; cursor[n] = off;
    }
}

// ---------------------------------------------------------------------------
// Kernel 4: scatter edges into CSR-by-dst; pack (src, d) as int2.
// (no dmax logic here — see calc_dmax)
// ---------------------------------------------------------------------------
__global__ __launch_bounds__(256) void scatter_edges(
    const float* __restrict__ pos, const int* __restrict__ ei,
    int* __restrict__ cursor, int2* __restrict__ csr, int Ee)
{
    int e = blockIdx.x * 256 + threadIdx.x;
    if (e >= Ee) return;
    int s  = ei[e];
    int dg = ei[Ee + e];
    float dx = pos[(size_t)dg * 3 + 0] - pos[(size_t)s * 3 + 0];
    float dy = pos[(size_t)dg * 3 + 1] - pos[(size_t)s * 3 + 1];
    float dz = pos[(size_t)dg * 3 + 2] - pos[(size_t)s * 3 + 2];
    float d = sqrtf(dx * dx + dy * dy + dz * dz) + 1e-8f;
    int p = atomicAdd(&cursor[dg], 1);
    int2 pk; pk.x = s; pk.y = __float_as_int(d);
    csr[p] = pk;
}

// ---------------------------------------------------------------------------
// Kernel 4b: dmax over csr[].y — grid-stride, block-reduced, ONE atomic/block
// (256 total same-address atomics; Guideline 12).
// ---------------------------------------------------------------------------
__global__ __launch_bounds__(256) void calc_dmax(
    const int2* __restrict__ csr, int* __restrict__ dmax_enc, int Ee)
{
    __shared__ float sred[4];
    float wm = 0.f;
    for (int e = blockIdx.x * 256 + threadIdx.x; e < Ee; e += gridDim.x * 256)
        wm = fmaxf(wm, __int_as_float(csr[e].y));
#pragma unroll
    for (int i = 1; i < 64; i <<= 1) wm = fmaxf(wm, __shfl_xor(wm, i));
    int w = threadIdx.x >> 6;
    if ((threadIdx.x & 63) == 0) sred[w] = wm;
    __syncthreads();
    if (threadIdx.x == 0) {
        float bm = fmaxf(fmaxf(sred[0], sred[1]), fmaxf(sred[2], sred[3]));
        atomicMax(dmax_enc, __float_as_int(bm));  // positive floats: int order ok
    }
}

// ---------------------------------------------------------------------------
// Kernel 5: radial lookup table over d in [0, dmax], G grid points.
//   TAB[g]: 96 u32 slots: [0..64) half2(rk0*rs, rk1*rs) at lane h*16+j,
//           [64..96) 64 u16 f16 rv.
// ---------------------------------------------------------------------------
__global__ __launch_bounds__(256) void build_tab(
    const float* __restrict__ R1, const float* __restrict__ b1,
    const float* __restrict__ R2, const float* __restrict__ b2,
    const int* __restrict__ dmax_enc, unsigned* __restrict__ TAB)
{
    int idx = blockIdx.x * 256 + threadIdx.x;
    if (idx >= RADIAL_G * 64) return;
    int g = idx >> 6, lane = idx & 63;
    int h = lane >> 4, j = lane & 15;
    float dmax = __int_as_float(*dmax_enc);
    float d = dmax * (float)g / (float)(RADIAL_G - 1);
    float rh[16];
#pragma unroll
    for (int r = 0; r < 16; ++r) {
        float x = fmaf(d, R1[h * 16 + r], b1[h * 16 + r]);
        rh[r] = x / (1.f + __expf(-x));
    }
    float rk0 = b2[h * 64 + j], rk1 = b2[h * 64 + j + 16], rv = b2[h * 64 + 32 + j];
#pragma unroll
    for (int r = 0; r < 16; ++r) {
        const float* row = R2 + (size_t)(h * 16 + r) * 64;
        rk0 = fmaf(rh[r], row[j], rk0);
        rk1 = fmaf(rh[r], row[j + 16], rk1);
        rv  = fmaf(rh[r], row[32 + j], rv);
    }
    const float rs = 0.17677669529663687f; // 1/sqrt(32) folded into rk
    TAB[(size_t)g * 96 + lane] = pack_h2(rk0 * rs, rk1 * rs);
    ((unsigned short*)(TAB + (size_t)g * 96 + 64))[lane] = pack_h1(rv);
}

// ---------------------------------------------------------------------------
// Kernel 6: fused per-node attention — table-driven radial, no online max.
// One wave per node. Lane: h=lane>>4, j=lane&15.
// ---------------------------------------------------------------------------
__global__ __launch_bounds__(256) void node_attn(
    const float* __restrict__ Qtab, const unsigned* __restrict__ KVt,
    const unsigned* __restrict__ TAB, const int2* __restrict__ csr,
    const int* __restrict__ offs, const int* __restrict__ deg,
    const int* __restrict__ batch, const int* __restrict__ dmax_enc,
    float* __restrict__ pooled, int Nn)
{
    int lane = threadIdx.x & 63;
    int h = lane >> 4, j = lane & 15;
    int n = blockIdx.x * 4 + (threadIdx.x >> 6);
    if (n >= Nn) return;
    int start = offs[n], cnt = deg[n];
    if (cnt == 0) return;

    float dscale = (float)(RADIAL_G - 1) / __int_as_float(*dmax_enc);
    float q0 = Qtab[(size_t)n * 128 + h * 32 + j];
    float q1 = Qtab[(size_t)n * 128 + h * 32 + j + 16];
    float l = 0.f, acc = 0.f;

    auto LD = [&](int ei, unsigned& ku, unsigned short& vu,
                  unsigned& tk, unsigned short& tv) {
        int2 pk = csr[ei];
        int g = (int)fminf(fmaf(__int_as_float(pk.y), dscale, 0.5f),
                           (float)(RADIAL_G - 1));
        const unsigned* tb = TAB + (size_t)g * 96;
        tk = tb[lane];
        tv = ((const unsigned short*)(tb + 64))[lane];
        const unsigned* kb = KVt + (size_t)pk.x * 96;
        ku = kb[lane];
        vu = ((const unsigned short*)(kb + 64))[lane];
    };

    int e = start, end = start + cnt;
    unsigned ku0 = 0, ku1 = 0, tk0 = 0, tk1 = 0;
    unsigned short vu0 = 0, vu1 = 0, tv0 = 0, tv1 = 0;
    if (e + 1 < end) { LD(e, ku0, vu0, tk0, tv0); LD(e + 1, ku1, vu1, tk1, tv1); }
    for (; e + 1 < end; e += 2) {
        unsigned cku0 = ku0, ctk0 = tk0, cku1 = ku1, ctk1 = tk1;
        unsigned short cvu0 = vu0, ctv0 = tv0, cvu1 = vu1, ctv1 = tv1;
        if (e + 3 < end) { LD(e + 2, ku0, vu0, tk0, tv0); LD(e + 3, ku1, vu1, tk1, tv1); }
        float kx0, ky0, rx0, ry0, kx1, ky1, rx1, ry1;
        unp_h2(cku0, kx0, ky0); unp_h2(ctk0, rx0, ry0);
        unp_h2(cku1, kx1, ky1); unp_h2(ctk1, rx1, ry1);
        float p0 = q0 * kx0 * rx0 + q1 * ky0 * ry0;
        float p1 = q0 * kx1 * rx1 + q1 * ky1 * ry1;
        p0 = row_allsum(p0);
        p1 = row_allsum(p1);
        float ex0 = __expf(fminf(p0, 80.f));
        float ex1 = __expf(fminf(p1, 80.f));
        l += ex0 + ex1;
        acc = fmaf(ex0, unp_h1(cvu0) * unp_h1(ctv0),
              fmaf(ex1, unp_h1(cvu1) * unp_h1(ctv1), acc));
    }
    if (e < end) {
        unsigned ku, tk; unsigned short vu, tv;
        LD(e, ku, vu, tk, tv);
        float kx, ky, rx, ry;
        unp_h2(ku, kx, ky); unp_h2(tk, rx, ry);
        float p = q0 * kx * rx + q1 * ky * ry;
        p = row_allsum(p);
        float ex = __expf(fminf(p, 80.f));
        l += ex;
        acc = fmaf(ex, unp_h1(vu) * unp_h1(tv), acc);
    }
    float o = acc / (l + 1e-30f);
    atomicAdd(&pooled[(size_t)batch[n] * 64 + lane], o);
}

// ---------------------------------------------------------------------------
// Kernel 7: out[b][o] = sum_i pooled[b][i] * Wproj[i][o]
// ---------------------------------------------------------------------------
__global__ __launch_bounds__(256) void final_proj(
    const float* __restrict__ pooled, const float* __restrict__ Wproj,
    float* __restrict__ out, int total)
{
    int idx = blockIdx.x * 256 + threadIdx.x;
    if (idx >= total) return;
    int b = idx >> 6, o = idx & 63;
    float acc = 0.f;
#pragma unroll
    for (int i = 0; i < 64; ++i) acc += pooled[b * 64 + i] * Wproj[i * 64 + o];
    out[idx] = acc;
}

extern "C" void kernel_launch(void* const* d_in, const int* in_sizes, int n_in,
                              void* d_out, int out_size, void* d_ws, size_t ws_size,
                              hipStream_t stream)
{
    const float* pos   = (const float*)d_in[0];
    const float* nf    = (const float*)d_in[1];
    const int*   ei    = (const int*)d_in[2];
    const int*   batch = (const int*)d_in[3];
    const float* W_emb = (const float*)d_in[4];
    const float* b_emb = (const float*)d_in[5];
    const float* Wq    = (const float*)d_in[6];
    const float* Wk    = (const float*)d_in[7];
    const float* Wv0   = (const float*)d_in[8];
    const float* R1    = (const float*)d_in[10];
    const float* b1    = (const float*)d_in[11];
    const float* R2    = (const float*)d_in[12];
    const float* b2    = (const float*)d_in[13];
    const float* Wproj = (const float*)d_in[14];
    float* out = (float*)d_out;

    long Nn = in_sizes[0] / 3;
    long Ee = in_sizes[2] / 2;
    int  Bb = out_size / 64;

    float* ws = (float*)d_ws;
    size_t o = 0;
    size_t WCOMB = o; o += 32 * 320;
    size_t BCOMB = o; o += 320;
    size_t QTAB  = o; o += (size_t)Nn * 128;
    size_t KVT   = o; o += (size_t)Nn * 96;
    size_t DEG   = o; o += (size_t)Nn;
    size_t GTOT  = o; o += 2;                  // [0]=edge-total cursor, [1]=dmax
    size_t POOL  = o; o += (size_t)Bb * 64;
    size_t OFFS  = o; o += (size_t)Nn;
    size_t CURS  = o; o += (size_t)Nn;
    o = (o + 1) & ~(size_t)1;                  // 8B-align csr
    size_t CSR   = o; o += (size_t)Ee * 2;
    size_t TAB   = o; o += (size_t)RADIAL_G * 96;

    // zero deg + gtot + dmax + pooled (contiguous)
    hipMemsetAsync(ws + DEG, 0,
                   ((size_t)Nn + 2 + (size_t)Bb * 64) * sizeof(float), stream);

    fold_weights<<<idiv_up(33 * 320, 256), 256, 0, stream>>>(
        W_emb, b_emb, Wq, Wk, Wv0, ws + WCOMB, ws + BCOMB);

    node_qkv<<<idiv_up(Nn, 256), 256, 0, stream>>>(
        nf, ws + WCOMB, ws + BCOMB, ws + QTAB, (unsigned*)(ws + KVT), (int)Nn);

    count_deg<<<idiv_up(Ee, 256), 256, 0, stream>>>(
        ei, (int*)(ws + DEG), (int)Ee);

    calc_offs<<<idiv_up(Nn, 256), 256, 0, stream>>>(
        (const int*)(ws + DEG), (int*)(ws + OFFS), (int*)(ws + CURS),
        (int*)(ws + GTOT), (int)Nn);

    scatter_edges<<<idiv_up(Ee, 256), 256, 0, stream>>>(
        pos, ei, (int*)(ws + CURS), (int2*)(ws + CSR), (int)Ee);

    calc_dmax<<<256, 256, 0, stream>>>(
        (const int2*)(ws + CSR), (int*)(ws + GTOT) + 1, (int)Ee);

    build_tab<<<idiv_up(RADIAL_G * 64, 256), 256, 0, stream>>>(
        R1, b1, R2, b2, (const int*)(ws + GTOT) + 1, (unsigned*)(ws + TAB));

    node_attn<<<idiv_up(Nn, 4), 256, 0, stream>>>(
        ws + QTAB, (const unsigned*)(ws + KVT), (const unsigned*)(ws + TAB),
        (const int2*)(ws + CSR), (const int*)(ws + OFFS),
        (const int*)(ws + DEG), batch, (const int*)(ws + GTOT) + 1,
        ws + POOL, (int)Nn);

    final_proj<<<idiv_up(out_size, 256), 256, 0, stream>>>(
        ws + POOL, Wproj, out, out_size);
}

// Round 9
// 259.672 us; speedup vs baseline: 1.5723x; 1.1443x over previous
//
#include <hip/hip_runtime.h>
#include <hip/hip_fp16.h>

static inline int idiv_up(long a, long b) { return (int)((a + b - 1) / b); }

#define RADIAL_G 2048

__device__ __forceinline__ unsigned pack_h2(float a, float b) {
    __half2 t = __floats2half2_rn(a, b);
    return *reinterpret_cast<unsigned*>(&t);
}
__device__ __forceinline__ unsigned short pack_h1(float a) {
    __half t = __float2half_rn(a);
    return *reinterpret_cast<unsigned short*>(&t);
}
__device__ __forceinline__ void unp_h2(unsigned u, float& lo, float& hi) {
    __half2 t = *reinterpret_cast<__half2*>(&u);
    lo = __half2float(__low2half(t));
    hi = __half2float(__high2half(t));
}
__device__ __forceinline__ float unp_h1(unsigned short u) {
    return __half2float(*reinterpret_cast<__half*>(&u));
}

// DPP cross-lane on the VALU pipe (no DS traffic).
template <int CTRL>
__device__ __forceinline__ float dppf(float x) {
    return __int_as_float(__builtin_amdgcn_update_dpp(
        0, __float_as_int(x), CTRL, 0xF, 0xF, true));
}
// all-lane sum within each 16-lane row
__device__ __forceinline__ float row_allsum(float p) {
    p += dppf<0xB1>(p);    // quad_perm xor1
    p += dppf<0x4E>(p);    // quad_perm xor2
    p += dppf<0x124>(p);   // row_ror:4
    p += dppf<0x128>(p);   // row_ror:8
    return p;
}

// ---------------------------------------------------------------------------
// Kernel 0: fold weights. Wcomb[f][j] = sum_c W_emb[f][c]*Wcat[c][j]
// j: [0,128)=Q (h=j>>5,k=j&31), [128,256)=K, [256,320)=V0
// ---------------------------------------------------------------------------
__global__ __launch_bounds__(256) void fold_weights(
    const float* __restrict__ W_emb, const float* __restrict__ b_emb,
    const float* __restrict__ Wq, const float* __restrict__ Wk,
    const float* __restrict__ Wv0,
    float* __restrict__ Wcomb, float* __restrict__ bcomb)
{
    int idx = blockIdx.x * 256 + threadIdx.x;
    if (idx >= 33 * 320) return;
    int row = idx / 320, j = idx - row * 320;
    float acc = 0.f;
    for (int c = 0; c < 64; ++c) {
        float w;
        if (j < 128)      { int h = j >> 5,         k = j & 31;         w = Wq [(h * 64 + c) * 32 + k]; }
        else if (j < 256) { int h = (j - 128) >> 5, k = (j - 128) & 31; w = Wk [(h * 64 + c) * 32 + k]; }
        else              { int h = (j - 256) >> 4, v = (j - 256) & 15; w = Wv0[(h * 64 + c) * 16 + v]; }
        float lhs = (row < 32) ? W_emb[row * 64 + c] : b_emb[c];
        acc += lhs * w;
    }
    if (row < 32) Wcomb[row * 320 + j] = acc;
    else          bcomb[j] = acc;
}

// ---------------------------------------------------------------------------
// Kernel 1: per-node tables; nf read ONCE per node.
//   Qtab[n][128] f32
//   KVt[n]: 96 u32 slots (384B): [0..64) = half2(k_j,k_j+16) at lane h*16+j;
//   [64..96) = 64 u16 f16 V at lane h*16+j.
// ---------------------------------------------------------------------------
__global__ __launch_bounds__(256) void node_qkv(
    const float* __restrict__ nf, const float* __restrict__ Wcomb,
    const float* __restrict__ bcomb, float* __restrict__ Qtab,
    unsigned* __restrict__ KVt, int Nn)
{
    __shared__ float sW[32][32];
    __shared__ float sb[32];
    int n = blockIdx.x * 256 + threadIdx.x;
    bool valid = n < Nn;

    float nfv[32];
    if (valid) {
        const float4* nfp = (const float4*)(nf + (size_t)n * 32);
#pragma unroll
        for (int f4 = 0; f4 < 8; ++f4) {
            float4 v = nfp[f4];
            nfv[f4 * 4 + 0] = v.x; nfv[f4 * 4 + 1] = v.y;
            nfv[f4 * 4 + 2] = v.z; nfv[f4 * 4 + 3] = v.w;
        }
    }
    for (int c = 0; c < 10; ++c) {
        __syncthreads();
        for (int i = threadIdx.x; i < 1024; i += 256) {
            int f = i >> 5, jj = i & 31;
            sW[f][jj] = Wcomb[f * 320 + c * 32 + jj];
        }
        if (threadIdx.x < 32) sb[threadIdx.x] = bcomb[c * 32 + threadIdx.x];
        __syncthreads();
        if (!valid) continue;

        float acc[32];
#pragma unroll
        for (int jj = 0; jj < 32; ++jj) acc[jj] = sb[jj];
#pragma unroll
        for (int f = 0; f < 32; ++f) {
            float x = nfv[f];
#pragma unroll
            for (int j4 = 0; j4 < 8; ++j4) {
                float4 w = *(const float4*)&sW[f][j4 * 4];
                acc[j4 * 4 + 0] += x * w.x; acc[j4 * 4 + 1] += x * w.y;
                acc[j4 * 4 + 2] += x * w.z; acc[j4 * 4 + 3] += x * w.w;
            }
        }
        if (c < 4) {
            float4* outp = (float4*)(Qtab + (size_t)n * 128 + c * 32);
#pragma unroll
            for (int j4 = 0; j4 < 8; ++j4) {
                float4 v;
                v.x = acc[j4 * 4 + 0]; v.y = acc[j4 * 4 + 1];
                v.z = acc[j4 * 4 + 2]; v.w = acc[j4 * 4 + 3];
                outp[j4] = v;
            }
        } else if (c < 8) {
            unsigned* kp = KVt + (size_t)n * 96 + (c - 4) * 16;
#pragma unroll
            for (int jj = 0; jj < 16; ++jj)
                kp[jj] = pack_h2(acc[jj], acc[jj + 16]);
        } else {
            unsigned short* vp = (unsigned short*)(KVt + (size_t)n * 96 + 64) + (c - 8) * 32;
#pragma unroll
            for (int jj = 0; jj < 32; ++jj) vp[jj] = pack_h1(acc[jj]);
        }
    }
}

// ---------------------------------------------------------------------------
// Kernel 2: degree count; atomic's RETURN value is the edge's rank within its
// dst segment — store it (free ordering info, removes scatter's atomic).
// ---------------------------------------------------------------------------
__global__ __launch_bounds__(256) void count_deg(
    const int* __restrict__ ei, int* __restrict__ deg,
    unsigned short* __restrict__ rank, int Ee)
{
    int e = blockIdx.x * 256 + threadIdx.x;
    if (e >= Ee) return;
    int r = atomicAdd(&deg[ei[Ee + e]], 1);
    rank[e] = (unsigned short)r;
}

// ---------------------------------------------------------------------------
// Kernel 3: offsets via wave prefix-sum + one atomic per wave (order-free).
// ---------------------------------------------------------------------------
__global__ __launch_bounds__(256) void calc_offs(
    const int* __restrict__ deg, int* __restrict__ offs,
    int* __restrict__ gtot, int Nn)
{
    int n = blockIdx.x * 256 + threadIdx.x;
    int lane = threadIdx.x & 63;
    int d = (n < Nn) ? deg[n] : 0;
    int pre = d;
#pragma unroll
    for (int s = 1; s < 64; s <<= 1) {
        int t = __shfl_up(pre, s);
        if (lane >= s) pre += t;
    }
    int waveTot = __shfl(pre, 63);
    int base = 0;
    if (lane == 63) base = atomicAdd(gtot, waveTot);
    base = __shfl(base, 63);
    if (n < Nn) offs[n] = base + pre - d;
}

// ---------------------------------------------------------------------------
// Kernel 4: scatter edges into CSR-by-dst — NO atomics: p = offs[dst]+rank[e].
// ---------------------------------------------------------------------------
__global__ __launch_bounds__(256) void scatter_edges(
    const float* __restrict__ pos, const int* __restrict__ ei,
    const int* __restrict__ offs, const unsigned short* __restrict__ rank,
    int2* __restrict__ csr, int Ee)
{
    int e = blockIdx.x * 256 + threadIdx.x;
    if (e >= Ee) return;
    int s  = ei[e];
    int dg = ei[Ee + e];
    float dx = pos[(size_t)dg * 3 + 0] - pos[(size_t)s * 3 + 0];
    float dy = pos[(size_t)dg * 3 + 1] - pos[(size_t)s * 3 + 1];
    float dz = pos[(size_t)dg * 3 + 2] - pos[(size_t)s * 3 + 2];
    float d = sqrtf(dx * dx + dy * dy + dz * dz) + 1e-8f;
    int p = offs[dg] + (int)rank[e];
    int2 pk; pk.x = s; pk.y = __float_as_int(d);
    csr[p] = pk;
}

// ---------------------------------------------------------------------------
// Kernel 4b: dmax over csr[].y — grid-stride, block-reduced, ONE atomic/block.
// ---------------------------------------------------------------------------
__global__ __launch_bounds__(256) void calc_dmax(
    const int2* __restrict__ csr, int* __restrict__ dmax_enc, int Ee)
{
    __shared__ float sred[4];
    float wm = 0.f;
    for (int e = blockIdx.x * 256 + threadIdx.x; e < Ee; e += gridDim.x * 256)
        wm = fmaxf(wm, __int_as_float(csr[e].y));
#pragma unroll
    for (int i = 1; i < 64; i <<= 1) wm = fmaxf(wm, __shfl_xor(wm, i));
    int w = threadIdx.x >> 6;
    if ((threadIdx.x & 63) == 0) sred[w] = wm;
    __syncthreads();
    if (threadIdx.x == 0) {
        float bm = fmaxf(fmaxf(sred[0], sred[1]), fmaxf(sred[2], sred[3]));
        atomicMax(dmax_enc, __float_as_int(bm));  // positive floats: int order ok
    }
}

// ---------------------------------------------------------------------------
// Kernel 5: radial lookup table over d in [0, dmax], G grid points.
// ---------------------------------------------------------------------------
__global__ __launch_bounds__(256) void build_tab(
    const float* __restrict__ R1, const float* __restrict__ b1,
    const float* __restrict__ R2, const float* __restrict__ b2,
    const int* __restrict__ dmax_enc, unsigned* __restrict__ TAB)
{
    int idx = blockIdx.x * 256 + threadIdx.x;
    if (idx >= RADIAL_G * 64) return;
    int g = idx >> 6, lane = idx & 63;
    int h = lane >> 4, j = lane & 15;
    float dmax = __int_as_float(*dmax_enc);
    float d = dmax * (float)g / (float)(RADIAL_G - 1);
    float rh[16];
#pragma unroll
    for (int r = 0; r < 16; ++r) {
        float x = fmaf(d, R1[h * 16 + r], b1[h * 16 + r]);
        rh[r] = x / (1.f + __expf(-x));
    }
    float rk0 = b2[h * 64 + j], rk1 = b2[h * 64 + j + 16], rv = b2[h * 64 + 32 + j];
#pragma unroll
    for (int r = 0; r < 16; ++r) {
        const float* row = R2 + (size_t)(h * 16 + r) * 64;
        rk0 = fmaf(rh[r], row[j], rk0);
        rk1 = fmaf(rh[r], row[j + 16], rk1);
        rv  = fmaf(rh[r], row[32 + j], rv);
    }
    const float rs = 0.17677669529663687f; // 1/sqrt(32) folded into rk
    TAB[(size_t)g * 96 + lane] = pack_h2(rk0 * rs, rk1 * rs);
    ((unsigned short*)(TAB + (size_t)g * 96 + 64))[lane] = pack_h1(rv);
}

// ---------------------------------------------------------------------------
// Kernel 6: fused per-node attention — table-driven radial, no online max,
// 3-pair-deep software pipeline (load->use distance = 8 edges).
// One wave per node. Lane: h=lane>>4, j=lane&15.
// ---------------------------------------------------------------------------
struct Pair {
    unsigned kuA, kuB, tkA, tkB;
    unsigned short vuA, vuB, tvA, tvB;
};

__global__ __launch_bounds__(256) void node_attn(
    const float* __restrict__ Qtab, const unsigned* __restrict__ KVt,
    const unsigned* __restrict__ TAB, const int2* __restrict__ csr,
    const int* __restrict__ offs, const int* __restrict__ deg,
    const int* __restrict__ batch, const int* __restrict__ dmax_enc,
    float* __restrict__ pooled, int Nn)
{
    int lane = threadIdx.x & 63;
    int h = lane >> 4, j = lane & 15;
    int n = blockIdx.x * 4 + (threadIdx.x >> 6);
    if (n >= Nn) return;
    int start = offs[n], cnt = deg[n];
    if (cnt == 0) return;

    float dscale = (float)(RADIAL_G - 1) / __int_as_float(*dmax_enc);
    float q0 = Qtab[(size_t)n * 128 + h * 32 + j];
    float q1 = Qtab[(size_t)n * 128 + h * 32 + j + 16];
    float l = 0.f, acc = 0.f;

    auto LD1 = [&](int ei, unsigned& ku, unsigned short& vu,
                   unsigned& tk, unsigned short& tv) {
        int2 pk = csr[ei];
        int g = (int)fminf(fmaf(__int_as_float(pk.y), dscale, 0.5f),
                           (float)(RADIAL_G - 1));
        const unsigned* tb = TAB + (size_t)g * 96;
        tk = tb[lane];
        tv = ((const unsigned short*)(tb + 64))[lane];
        const unsigned* kb = KVt + (size_t)pk.x * 96;
        ku = kb[lane];
        vu = ((const unsigned short*)(kb + 64))[lane];
    };
    auto LDP = [&](Pair& P, int ei) {
        LD1(ei,     P.kuA, P.vuA, P.tkA, P.tvA);
        LD1(ei + 1, P.kuB, P.vuB, P.tkB, P.tvB);
    };
    auto CMP = [&](const Pair& P) {
        float kx0, ky0, rx0, ry0, kx1, ky1, rx1, ry1;
        unp_h2(P.kuA, kx0, ky0); unp_h2(P.tkA, rx0, ry0);
        unp_h2(P.kuB, kx1, ky1); unp_h2(P.tkB, rx1, ry1);
        float p0 = q0 * kx0 * rx0 + q1 * ky0 * ry0;
        float p1 = q0 * kx1 * rx1 + q1 * ky1 * ry1;
        p0 = row_allsum(p0);
        p1 = row_allsum(p1);
        float ex0 = __expf(fminf(p0, 80.f));
        float ex1 = __expf(fminf(p1, 80.f));
        l += ex0 + ex1;
        acc = fmaf(ex0, unp_h1(P.vuA) * unp_h1(P.tvA),
              fmaf(ex1, unp_h1(P.vuB) * unp_h1(P.tvB), acc));
    };

    int e = start, end = start + cnt;
    Pair A, B, NA, NB;
    if (e + 3 < end) {
        LDP(A, e); LDP(B, e + 2);
#pragma unroll 2
        for (; e + 7 < end; e += 4) {
            LDP(NA, e + 4); LDP(NB, e + 6);
            CMP(A); CMP(B);
            A = NA; B = NB;
        }
        CMP(A); CMP(B);
        e += 4;
    }
    for (; e + 1 < end; e += 2) { LDP(A, e); CMP(A); }
    if (e < end) {
        unsigned ku, tk; unsigned short vu, tv;
        LD1(e, ku, vu, tk, tv);
        float kx, ky, rx, ry;
        unp_h2(ku, kx, ky); unp_h2(tk, rx, ry);
        float p = q0 * kx * rx + q1 * ky * ry;
        p = row_allsum(p);
        float ex = __expf(fminf(p, 80.f));
        l += ex;
        acc = fmaf(ex, unp_h1(vu) * unp_h1(tv), acc);
    }
    float o = acc / (l + 1e-30f);
    atomicAdd(&pooled[(size_t)batch[n] * 64 + lane], o);
}

// ---------------------------------------------------------------------------
// Kernel 7: out[b][o] = sum_i pooled[b][i] * Wproj[i][o]
// ---------------------------------------------------------------------------
__global__ __launch_bounds__(256) void final_proj(
    const float* __restrict__ pooled, const float* __restrict__ Wproj,
    float* __restrict__ out, int total)
{
    int idx = blockIdx.x * 256 + threadIdx.x;
    if (idx >= total) return;
    int b = idx >> 6, o = idx & 63;
    float acc = 0.f;
#pragma unroll
    for (int i = 0; i < 64; ++i) acc += pooled[b * 64 + i] * Wproj[i * 64 + o];
    out[idx] = acc;
}

extern "C" void kernel_launch(void* const* d_in, const int* in_sizes, int n_in,
                              void* d_out, int out_size, void* d_ws, size_t ws_size,
                              hipStream_t stream)
{
    const float* pos   = (const float*)d_in[0];
    const float* nf    = (const float*)d_in[1];
    const int*   ei    = (const int*)d_in[2];
    const int*   batch = (const int*)d_in[3];
    const float* W_emb = (const float*)d_in[4];
    const float* b_emb = (const float*)d_in[5];
    const float* Wq    = (const float*)d_in[6];
    const float* Wk    = (const float*)d_in[7];
    const float* Wv0   = (const float*)d_in[8];
    const float* R1    = (const float*)d_in[10];
    const float* b1    = (const float*)d_in[11];
    const float* R2    = (const float*)d_in[12];
    const float* b2    = (const float*)d_in[13];
    const float* Wproj = (const float*)d_in[14];
    float* out = (float*)d_out;

    long Nn = in_sizes[0] / 3;
    long Ee = in_sizes[2] / 2;
    int  Bb = out_size / 64;

    float* ws = (float*)d_ws;
    size_t o = 0;
    size_t WCOMB = o; o += 32 * 320;
    size_t BCOMB = o; o += 320;
    size_t QTAB  = o; o += (size_t)Nn * 128;
    size_t KVT   = o; o += (size_t)Nn * 96;
    size_t DEG   = o; o += (size_t)Nn;
    size_t GTOT  = o; o += 2;                  // [0]=edge-total cursor, [1]=dmax
    size_t POOL  = o; o += (size_t)Bb * 64;
    size_t OFFS  = o; o += (size_t)Nn;
    o = (o + 1) & ~(size_t)1;                  // 8B-align csr
    size_t CSR   = o; o += (size_t)Ee * 2;
    size_t TAB   = o; o += (size_t)RADIAL_G * 96;
    size_t RANK  = o; o += (Ee + 1) / 2;       // u16 per edge

    // zero deg + gtot + dmax + pooled (contiguous)
    hipMemsetAsync(ws + DEG, 0,
                   ((size_t)Nn + 2 + (size_t)Bb * 64) * sizeof(float), stream);

    fold_weights<<<idiv_up(33 * 320, 256), 256, 0, stream>>>(
        W_emb, b_emb, Wq, Wk, Wv0, ws + WCOMB, ws + BCOMB);

    node_qkv<<<idiv_up(Nn, 256), 256, 0, stream>>>(
        nf, ws + WCOMB, ws + BCOMB, ws + QTAB, (unsigned*)(ws + KVT), (int)Nn);

    count_deg<<<idiv_up(Ee, 256), 256, 0, stream>>>(
        ei, (int*)(ws + DEG), (unsigned short*)(ws + RANK), (int)Ee);

    calc_offs<<<idiv_up(Nn, 256), 256, 0, stream>>>(
        (const int*)(ws + DEG), (int*)(ws + OFFS), (int*)(ws + GTOT), (int)Nn);

    scatter_edges<<<idiv_up(Ee, 256), 256, 0, stream>>>(
        pos, ei, (const int*)(ws + OFFS), (const unsigned short*)(ws + RANK),
        (int2*)(ws + CSR), (int)Ee);

    calc_dmax<<<256, 256, 0, stream>>>(
        (const int2*)(ws + CSR), (int*)(ws + GTOT) + 1, (int)Ee);

    build_tab<<<idiv_up(RADIAL_G * 64, 256), 256, 0, stream>>>(
        R1, b1, R2, b2, (const int*)(ws + GTOT) + 1, (unsigned*)(ws + TAB));

    node_attn<<<idiv_up(Nn, 4), 256, 0, stream>>>(
        ws + QTAB, (const unsigned*)(ws + KVT), (const unsigned*)(ws + TAB),
        (const int2*)(ws + CSR), (const int*)(ws + OFFS),
        (const int*)(ws + DEG), batch, (const int*)(ws + GTOT) + 1,
        ws + POOL, (int)Nn);

    final_proj<<<idiv_up(out_size, 256), 256, 0, stream>>>(
        ws + POOL, Wproj, out, out_size);
}